// Round 14
// baseline (27.902 us; speedup 1.0000x reference)
//
#include <hip/hip_runtime.h>
#include <math.h>

#define NPTS 4096
#define BLK2 512                     // scan block threads (8 waves)
#define NUNITS 16                    // 8 batches * 2 directions
#define QGRP 64                      // queries per scan block
#define QGRPS 64                     // query groups per unit
#define GRID1 (NUNITS * QGRPS)       // 1024 scan blocks (4/CU, 32 waves/CU)
#define PHT 1024                     // targets staged per LDS phase
#define NPH 4                        // phases
#define CNT 12288.0f                 // N*D elements per std

typedef _Float16 half8 __attribute__((ext_vector_type(8)));
typedef float f32x16 __attribute__((ext_vector_type(16)));

__device__ __forceinline__ unsigned umin2(unsigned a, unsigned b) { return a < b ? a : b; }
__device__ __forceinline__ float fmin3(float a, float b, float c) {
  return fminf(fminf(a, b), c);      // fuses to v_min3_f32
}

// min over the 16 f32 accumulator regs of one 32x32 MFMA result
__device__ __forceinline__ float tilemin16(const f32x16 d) {
  const float a0 = fmin3(d[0],  d[1],  d[2]);
  const float a1 = fmin3(d[3],  d[4],  d[5]);
  const float a2 = fmin3(d[6],  d[7],  d[8]);
  const float a3 = fmin3(d[9],  d[10], d[11]);
  const float a4 = fmin3(d[12], d[13], d[14]);
  return fminf(fmin3(a0, a1, a2), fmin3(a3, a4, d[15]));
}

// ---------------------------------------------------------------------------
// Kernel 1: FULL-SCAN fused NN at MAX OCCUPANCY (32 waves/CU, 8/SIMD).
// Block = (unit, 64-query group), 8 waves: wave (qt, th) scans query-tile qt
// (32 queries) over target-quarter th (1024 targets, 8 tiles per phase x 4
// phases of 1024 staged targets). Hierarchical argmin key (trunc tile-min d2
// | global-tile-id, proven r5-r13) stays in-register; quarters merge via one
// LDS u32 min round (disjoint tile-id ranges keep first-index tie-break);
// th=0 waves rescan the winning 32-target tile from L2 in exact fp32.
// fp16-split d2 via ONE 32x32x16 f16 MFMA per tile (proven r3+):
//  k0-2: bh*(-2ah)  k3-5: bl*(-2ah)  k6-8: bh*(-2al)
//  k9,10: b2{h,l}*1  k11,12: 1*a2{h,l}  k13-15: 0
// ---------------------------------------------------------------------------
__global__ __launch_bounds__(BLK2, 8) void fullscan_kernel(
    const float* __restrict__ x, const float* __restrict__ y,
    float2* __restrict__ partials) {
  __shared__ half8 Ap[2 * PHT];        // 32 KB: plane [hi5][1024 targets]
  __shared__ half8 Bq[2 * QGRP];       //  2 KB: plane [hi5][64 queries]
  __shared__ unsigned km[2][4][32];    //  1 KB: cross-quarter key merge
  __shared__ float wS[8], wSS[8];

  const int bid  = blockIdx.x;
  const int unit = bid >> 6, qg = bid & 63;
  const int b = unit >> 1, dir = unit & 1;
  const float* __restrict__ Q = (dir ? y : x) + (size_t)b * NPTS * 3;  // queries
  const float* __restrict__ T = (dir ? x : y) + (size_t)b * NPTS * 3;  // targets

  const int tid = threadIdx.x;
  const _Float16 one  = (_Float16)1.0f;
  const _Float16 zero = (_Float16)0.0f;
  const _Float16 n2   = (_Float16)(-2.0f);

  // ---- pack this block's 64 queries (threads 0..127: plane x 64) ----
  if (tid < 2 * QGRP) {
    const int plane = tid >> 6, qi = tid & 63;
    const int qq = qg * QGRP + qi;
    const float ax = Q[3 * qq], ay = Q[3 * qq + 1], az = Q[3 * qq + 2];
    const float a2 = fmaf(ax, ax, fmaf(ay, ay, az * az));
    const _Float16 ah0 = (_Float16)ax, ah1 = (_Float16)ay, ah2 = (_Float16)az;
    const _Float16 al0 = (_Float16)(ax - (float)ah0);
    const _Float16 al1 = (_Float16)(ay - (float)ah1);
    const _Float16 al2 = (_Float16)(az - (float)ah2);
    const _Float16 a2h = (_Float16)a2;
    const _Float16 a2l = (_Float16)(a2 - (float)a2h);
    half8 v;
    if (plane == 0) {
      v[0] = n2 * ah0; v[1] = n2 * ah1; v[2] = n2 * ah2; v[3] = n2 * ah0;
      v[4] = n2 * ah1; v[5] = n2 * ah2; v[6] = n2 * al0; v[7] = n2 * al1;
    } else {
      v[0] = n2 * al2; v[1] = one; v[2] = one; v[3] = a2h;
      v[4] = a2l; v[5] = zero; v[6] = zero; v[7] = zero;
    }
    Bq[plane * QGRP + qi] = v;
  }

  const int lane = tid & 63, w = tid >> 6, ln = lane & 31, hi5 = lane >> 5;
  const int qt = w >> 2, th = w & 3;       // query tile, target quarter
  unsigned kacc = 0xFFFFFFFFu;
  f32x16 Z;
  #pragma unroll
  for (int r = 0; r < 16; ++r) Z[r] = 0.0f;

  half8 bf;
  for (int c = 0; c < NPH; ++c) {
    if (c > 0) __syncthreads();            // all waves done reading prev Ap
    // ---- stage 1024 targets into LDS (2 per thread) ----
    #pragma unroll
    for (int k = 0; k < 2; ++k) {
      const int i  = tid + k * BLK2;       // 0..1023
      const int tg = c * PHT + i;
      const float bx = T[3 * tg], by = T[3 * tg + 1], bz = T[3 * tg + 2];
      const float b2 = fmaf(bx, bx, fmaf(by, by, bz * bz));
      const _Float16 bh0 = (_Float16)bx, bh1 = (_Float16)by, bh2 = (_Float16)bz;
      const _Float16 bl0 = (_Float16)(bx - (float)bh0);
      const _Float16 bl1 = (_Float16)(by - (float)bh1);
      const _Float16 bl2 = (_Float16)(bz - (float)bh2);
      const _Float16 s2h = (_Float16)b2;
      const _Float16 s2l = (_Float16)(b2 - (float)s2h);
      half8 lo, hi;
      lo[0] = bh0; lo[1] = bh1; lo[2] = bh2; lo[3] = bl0;
      lo[4] = bl1; lo[5] = bl2; lo[6] = bh0; lo[7] = bh1;
      hi[0] = bh2; hi[1] = s2h; hi[2] = s2l; hi[3] = one;
      hi[4] = one; hi[5] = zero; hi[6] = zero; hi[7] = zero;
      Ap[i]       = lo;
      Ap[PHT + i] = hi;
    }
    __syncthreads();                       // staging (and c=0: Bq) visible
    if (c == 0) bf = Bq[hi5 * QGRP + qt * 32 + ln];

    // wave scans its 256-target quarter of this phase: 8 tiles
    const unsigned cb = (unsigned)(c * 32 + th * 8);  // global tile id base
    const int abase = hi5 * PHT + th * 256;
    #pragma unroll
    for (int t = 0; t < 8; ++t) {
      const half8 af = Ap[abase + t * 32 + ln];
      const f32x16 d = __builtin_amdgcn_mfma_f32_32x32x16_f16(af, bf, Z, 0, 0, 0);
      kacc = umin2(kacc,
          (__float_as_uint(tilemin16(d)) & 0xFFFFF000u) | (cb + (unsigned)t));
    }
  }
  kacc = umin2(kacc, (unsigned)__shfl_xor((int)kacc, 32));   // merge row halves

  // ---- merge target quarters via LDS ----
  if (th != 0 && lane < 32) km[qt][th][ln] = kacc;
  __syncthreads();

  // ---- exact fp32 rescan of winning 32-target tile (th=0 waves, lane<32) --
  float s = 0.f, ss = 0.f;
  if (th == 0 && lane < 32) {
    kacc = umin2(umin2(kacc, km[qt][1][ln]),
                 umin2(km[qt][2][ln], km[qt][3][ln]));
    const int q = qg * QGRP + qt * 32 + ln;
    const int tbase = (int)(kacc & 4095u) * 32;      // payload = global tile id
    const float qx = Q[3 * q], qy = Q[3 * q + 1], qz = Q[3 * q + 2];
    unsigned best = 0xFFFFFFFFu;
    #pragma unroll 8
    for (int i = 0; i < 32; ++i) {
      const int j = tbase + i;
      const float dx = qx - T[3 * j];
      const float dy = qy - T[3 * j + 1];
      const float dz = qz - T[3 * j + 2];
      const float d2 = fmaf(dx, dx, fmaf(dy, dy, dz * dz));
      best = umin2(best, (__float_as_uint(d2) & 0xFFFFFFE0u) | (unsigned)i);
    }
    const int j = tbase + (int)(best & 31u);
    const float rx = qx - T[3 * j];
    const float ry = qy - T[3 * j + 1];
    const float rz = qz - T[3 * j + 2];
    s  = rx + ry + rz;
    ss = fmaf(rx, rx, fmaf(ry, ry, rz * rz));
  }

  #pragma unroll
  for (int off = 32; off > 0; off >>= 1) {
    s  += __shfl_down(s, off);
    ss += __shfl_down(ss, off);
  }
  if ((tid & 63) == 0) { wS[w] = s; wSS[w] = ss; }
  __syncthreads();
  if (tid == 0) {
    float S = 0.f, SS = 0.f;
    #pragma unroll
    for (int i = 0; i < 8; ++i) { S += wS[i]; SS += wSS[i]; }
    partials[bid] = make_float2(S, SS);
  }
}

// ---------------------------------------------------------------------------
// Kernel 2: deterministic finalize over 1024 partials (64 per unit).
// ---------------------------------------------------------------------------
__global__ __launch_bounds__(256) void finalize_kernel(
    const float2* __restrict__ partials, float* __restrict__ out) {
  __shared__ float2 sh[GRID1];   // 8 KB
  __shared__ float sig[NUNITS];

  #pragma unroll
  for (int k = 0; k < 4; ++k)
    sh[threadIdx.x + k * 256] = partials[threadIdx.x + k * 256];
  __syncthreads();

  if (threadIdx.x < NUNITS) {
    float S = 0.f, SS = 0.f;
    for (int i = 0; i < QGRPS; ++i) {
      S  += sh[threadIdx.x * QGRPS + i].x;
      SS += sh[threadIdx.x * QGRPS + i].y;
    }
    const float var = (SS - S * S / CNT) / (CNT - 1.0f);
    sig[threadIdx.x] = sqrtf(fmaxf(var, 0.0f));
  }
  __syncthreads();

  if (threadIdx.x == 0) {
    float acc = 0.f;
    #pragma unroll
    for (int b = 0; b < 8; ++b) acc += fmaxf(sig[2 * b], sig[2 * b + 1]);
    out[0] = acc * 0.125f;
  }
}

// ---------------------------------------------------------------------------
extern "C" void kernel_launch(void* const* d_in, const int* in_sizes, int n_in,
                              void* d_out, int out_size, void* d_ws, size_t ws_size,
                              hipStream_t stream) {
  const float* x = (const float*)d_in[0];
  const float* y = (const float*)d_in[1];
  float* out = (float*)d_out;
  float2* partials = (float2*)d_ws;   // 1024 * 8 B = 8 KB scratch

  hipLaunchKernelGGL(fullscan_kernel, dim3(GRID1), dim3(BLK2), 0, stream,
                     x, y, partials);
  hipLaunchKernelGGL(finalize_kernel, dim3(1), dim3(256), 0, stream,
                     partials, out);
}

// Round 15
// 23.307 us; speedup vs baseline: 1.1971x; 1.1971x over previous
//
#include <hip/hip_runtime.h>
#include <math.h>

#define NPTS 4096
#define BLK 256
#define NUNITS 16                    // 8 batches * 2 directions
#define QGRP 128                     // queries per block
#define QGRPS 32                     // query groups per unit
#define GRID1 (NUNITS * QGRPS)       // 512 blocks (2 per CU)
#define PHT 2048                     // targets staged per LDS phase
#define CNT 12288.0f                 // N*D elements per std

typedef _Float16 half8 __attribute__((ext_vector_type(8)));
typedef float f32x16 __attribute__((ext_vector_type(16)));

__device__ __forceinline__ unsigned umin2(unsigned a, unsigned b) { return a < b ? a : b; }
__device__ __forceinline__ float fmin3(float a, float b, float c) {
  return fminf(fminf(a, b), c);      // fuses to v_min3_f32
}

// min over the 16 f32 accumulator regs of one 32x32 MFMA result
__device__ __forceinline__ float tilemin16(const f32x16 d) {
  const float a0 = fmin3(d[0],  d[1],  d[2]);
  const float a1 = fmin3(d[3],  d[4],  d[5]);
  const float a2 = fmin3(d[6],  d[7],  d[8]);
  const float a3 = fmin3(d[9],  d[10], d[11]);
  const float a4 = fmin3(d[12], d[13], d[14]);
  return fminf(fmin3(a0, a1, a2), fmin3(a3, a4, d[15]));
}

// ---------------------------------------------------------------------------
// Kernel 1: FULL-SCAN fused NN (session-best structure, round 11; 23.3 µs).
// Block = (unit, 128-query group); scans all 4096 targets in two
// 2048-target LDS phases, so the hierarchical argmin key (trunc tile-min d2
// | tile-id) is FINAL in-block: no keys round-trip, no resolve dispatch.
// lane<32 rescans its query's winning 32-target tile from L2 in exact fp32
// (first-index tie-break) and the block emits one float2 (sum,sumsq) partial.
// fp16-split d2 via ONE 32x32x16 f16 MFMA per tile:
//  k0-2: bh*(-2ah)  k3-5: bl*(-2ah)  k6-8: bh*(-2al)
//  k9,10: b2{h,l}*1  k11,12: 1*a2{h,l}  k13-15: 0
// ---------------------------------------------------------------------------
__global__ __launch_bounds__(BLK, 2) void fullscan_kernel(
    const float* __restrict__ x, const float* __restrict__ y,
    float2* __restrict__ partials) {
  __shared__ half8 Ap[2 * PHT];    // 64 KB: plane [hi5][2048 targets]
  __shared__ half8 Bq[2 * QGRP];   //  4 KB: plane [hi5][128 queries]
  __shared__ float wS[4], wSS[4];

  const int bid  = blockIdx.x;
  const int unit = bid >> 5, qg = bid & 31;
  const int b = unit >> 1, dir = unit & 1;
  const float* __restrict__ Q = (dir ? y : x) + (size_t)b * NPTS * 3;  // queries
  const float* __restrict__ T = (dir ? x : y) + (size_t)b * NPTS * 3;  // targets

  const int tid = threadIdx.x;
  const _Float16 one  = (_Float16)1.0f;
  const _Float16 zero = (_Float16)0.0f;
  const _Float16 n2   = (_Float16)(-2.0f);

  // ---- pack this block's 128 queries (threads 0..127) ----
  if (tid < QGRP) {
    const int qq = qg * QGRP + tid;
    const float ax = Q[3 * qq], ay = Q[3 * qq + 1], az = Q[3 * qq + 2];
    const float a2 = fmaf(ax, ax, fmaf(ay, ay, az * az));
    const _Float16 ah0 = (_Float16)ax, ah1 = (_Float16)ay, ah2 = (_Float16)az;
    const _Float16 al0 = (_Float16)(ax - (float)ah0);
    const _Float16 al1 = (_Float16)(ay - (float)ah1);
    const _Float16 al2 = (_Float16)(az - (float)ah2);
    const _Float16 a2h = (_Float16)a2;
    const _Float16 a2l = (_Float16)(a2 - (float)a2h);
    half8 lo, hi;
    lo[0] = n2 * ah0; lo[1] = n2 * ah1; lo[2] = n2 * ah2; lo[3] = n2 * ah0;
    lo[4] = n2 * ah1; lo[5] = n2 * ah2; lo[6] = n2 * al0; lo[7] = n2 * al1;
    hi[0] = n2 * al2; hi[1] = one; hi[2] = one; hi[3] = a2h;
    hi[4] = a2l; hi[5] = zero; hi[6] = zero; hi[7] = zero;
    Bq[tid]        = lo;
    Bq[QGRP + tid] = hi;
  }

  const int lane = tid & 63, w = tid >> 6, ln = lane & 31, hi5 = lane >> 5;
  unsigned kacc0 = 0xFFFFFFFFu, kacc1 = 0xFFFFFFFFu;
  f32x16 Z;
  #pragma unroll
  for (int r = 0; r < 16; ++r) Z[r] = 0.0f;

  half8 bf;
  for (int c = 0; c < 2; ++c) {
    __syncthreads();   // c=0: covers Bq writes; c=1: all waves done with Ap
    // ---- stage 2048 targets into LDS (8 per thread) ----
    #pragma unroll
    for (int k = 0; k < 8; ++k) {
      const int i  = tid + k * BLK;          // 0..2047
      const int tg = c * PHT + i;
      const float bx = T[3 * tg], by = T[3 * tg + 1], bz = T[3 * tg + 2];
      const float b2 = fmaf(bx, bx, fmaf(by, by, bz * bz));
      const _Float16 bh0 = (_Float16)bx, bh1 = (_Float16)by, bh2 = (_Float16)bz;
      const _Float16 bl0 = (_Float16)(bx - (float)bh0);
      const _Float16 bl1 = (_Float16)(by - (float)bh1);
      const _Float16 bl2 = (_Float16)(bz - (float)bh2);
      const _Float16 s2h = (_Float16)b2;
      const _Float16 s2l = (_Float16)(b2 - (float)s2h);
      half8 lo, hi;
      lo[0] = bh0; lo[1] = bh1; lo[2] = bh2; lo[3] = bl0;
      lo[4] = bl1; lo[5] = bl2; lo[6] = bh0; lo[7] = bh1;
      hi[0] = bh2; hi[1] = s2h; hi[2] = s2l; hi[3] = one;
      hi[4] = one; hi[5] = zero; hi[6] = zero; hi[7] = zero;
      Ap[i]       = lo;
      Ap[PHT + i] = hi;
    }
    __syncthreads();
    if (c == 0) bf = Bq[hi5 * QGRP + w * 32 + ln];   // wave w owns one col tile

    const unsigned cb = (unsigned)(c * (PHT / 32));
    #pragma unroll 4
    for (int t = 0; t < PHT / 32; ++t) {             // 64 tiles per phase
      const half8 af = Ap[hi5 * PHT + t * 32 + ln];
      const f32x16 d = __builtin_amdgcn_mfma_f32_32x32x16_f16(af, bf, Z, 0, 0, 0);
      const unsigned key = (__float_as_uint(tilemin16(d)) & 0xFFFFF000u) | (cb + (unsigned)t);
      if (t & 1) kacc1 = umin2(kacc1, key);
      else       kacc0 = umin2(kacc0, key);
    }
  }
  unsigned kacc = umin2(kacc0, kacc1);
  kacc = umin2(kacc, (unsigned)__shfl_xor((int)kacc, 32));   // merge 16-row halves

  // ---- exact fp32 rescan of the winning 32-target tile (lane < 32) ----
  float s = 0.f, ss = 0.f;
  if (lane < 32) {
    const int q = qg * QGRP + w * 32 + ln;
    const int tbase = (int)(kacc & 4095u) * 32;      // payload = global tile id
    const float qx = Q[3 * q], qy = Q[3 * q + 1], qz = Q[3 * q + 2];
    unsigned best = 0xFFFFFFFFu;
    #pragma unroll 8
    for (int i = 0; i < 32; ++i) {
      const int j = tbase + i;
      const float dx = qx - T[3 * j];
      const float dy = qy - T[3 * j + 1];
      const float dz = qz - T[3 * j + 2];
      const float d2 = fmaf(dx, dx, fmaf(dy, dy, dz * dz));
      best = umin2(best, (__float_as_uint(d2) & 0xFFFFFFE0u) | (unsigned)i);
    }
    const int j = tbase + (int)(best & 31u);
    const float rx = qx - T[3 * j];
    const float ry = qy - T[3 * j + 1];
    const float rz = qz - T[3 * j + 2];
    s  = rx + ry + rz;
    ss = fmaf(rx, rx, fmaf(ry, ry, rz * rz));
  }

  #pragma unroll
  for (int off = 32; off > 0; off >>= 1) {
    s  += __shfl_down(s, off);
    ss += __shfl_down(ss, off);
  }
  if ((tid & 63) == 0) { wS[w] = s; wSS[w] = ss; }
  __syncthreads();
  if (tid == 0) {
    partials[bid] = make_float2(wS[0] + wS[1] + wS[2] + wS[3],
                                wSS[0] + wSS[1] + wSS[2] + wSS[3]);
  }
}

// ---------------------------------------------------------------------------
// Kernel 2: deterministic finalize over 512 partials (32 per unit).
// ---------------------------------------------------------------------------
__global__ __launch_bounds__(BLK) void finalize_kernel(
    const float2* __restrict__ partials, float* __restrict__ out) {
  __shared__ float2 sh[GRID1];
  __shared__ float sig[NUNITS];

  sh[threadIdx.x]       = partials[threadIdx.x];
  sh[threadIdx.x + BLK] = partials[threadIdx.x + BLK];
  __syncthreads();

  if (threadIdx.x < NUNITS) {
    float S = 0.f, SS = 0.f;
    #pragma unroll
    for (int i = 0; i < QGRPS; ++i) {
      S  += sh[threadIdx.x * QGRPS + i].x;
      SS += sh[threadIdx.x * QGRPS + i].y;
    }
    const float var = (SS - S * S / CNT) / (CNT - 1.0f);
    sig[threadIdx.x] = sqrtf(fmaxf(var, 0.0f));
  }
  __syncthreads();

  if (threadIdx.x == 0) {
    float acc = 0.f;
    #pragma unroll
    for (int b = 0; b < 8; ++b) acc += fmaxf(sig[2 * b], sig[2 * b + 1]);
    out[0] = acc * 0.125f;
  }
}

// ---------------------------------------------------------------------------
extern "C" void kernel_launch(void* const* d_in, const int* in_sizes, int n_in,
                              void* d_out, int out_size, void* d_ws, size_t ws_size,
                              hipStream_t stream) {
  const float* x = (const float*)d_in[0];
  const float* y = (const float*)d_in[1];
  float* out = (float*)d_out;
  float2* partials = (float2*)d_ws;   // 512 * 8 B = 4 KB scratch

  hipLaunchKernelGGL(fullscan_kernel, dim3(GRID1), dim3(BLK), 0, stream,
                     x, y, partials);
  hipLaunchKernelGGL(finalize_kernel, dim3(1), dim3(BLK), 0, stream,
                     partials, out);
}